// Round 11
// baseline (269.354 us; speedup 1.0000x reference)
//
#include <hip/hip_runtime.h>
#include <stdint.h>

#define D_ 384
#define NPTS 4096
// ws layout (floats): w4 [32*16*384] @0, w8 [32*64*384] @196608, w16 [32*256*384] @983040
#define W4_OFF 0
#define W8_OFF 196608
#define W16_OFF 983040
#define KM_REPS 10   // PROBE (this round): x10 internal repeat to surface kmeans in rocprof

// ---------------- Threefry-2x32 (JAX-exact, 20 rounds) ----------------
__device__ __forceinline__ void tf_round(uint32_t& x0, uint32_t& x1, int r) {
  x0 += x1;
  x1 = (x1 << r) | (x1 >> (32 - r));
  x1 ^= x0;
}

__device__ void tf2x32(uint32_t k0, uint32_t k1, uint32_t x0, uint32_t x1,
                       uint32_t& y0, uint32_t& y1) {
  uint32_t ks2 = k0 ^ k1 ^ 0x1BD11BDAu;
  x0 += k0; x1 += k1;
  tf_round(x0, x1, 13); tf_round(x0, x1, 15); tf_round(x0, x1, 26); tf_round(x0, x1, 6);
  x0 += k1; x1 += ks2 + 1u;
  tf_round(x0, x1, 17); tf_round(x0, x1, 29); tf_round(x0, x1, 16); tf_round(x0, x1, 24);
  x0 += ks2; x1 += k0 + 2u;
  tf_round(x0, x1, 13); tf_round(x0, x1, 15); tf_round(x0, x1, 26); tf_round(x0, x1, 6);
  x0 += k0; x1 += k1 + 3u;
  tf_round(x0, x1, 17); tf_round(x0, x1, 29); tf_round(x0, x1, 16); tf_round(x0, x1, 24);
  x0 += k1; x1 += ks2 + 4u;
  tf_round(x0, x1, 13); tf_round(x0, x1, 15); tf_round(x0, x1, 26); tf_round(x0, x1, 6);
  x0 += ks2; x1 += k0 + 5u;
  y0 = x0; y1 = x1;
}

// ---------------- pool16: MEASURED ~31 us, HBM floor. Done. ----------------
__global__ __launch_bounds__(384) void pool16_kernel(const float* __restrict__ feats,
                                                     float* __restrict__ ws) {
  int blk = blockIdx.x;
  int b = blk >> 6;
  int cell = ((blk & 63) << 2) + threadIdx.y;
  int q = threadIdx.x;                 // 0..95
  int ch = cell >> 4, cw = cell & 15;
  const float* fb = feats + (size_t)b * NPTS * D_;
  float ax = 0.f, ay = 0.f, az = 0.f, aw = 0.f;
  #pragma unroll
  for (int dh = 0; dh < 4; ++dh) {
    int h = ch * 4 + dh;
    #pragma unroll
    for (int dw = 0; dw < 4; ++dw) {
      int w = cw * 4 + dw;
      float4 v = *(const float4*)(fb + ((size_t)(h * 64 + w)) * D_ + q * 4);
      ax += v.x; ay += v.y; az += v.z; aw += v.w;
    }
  }
  float4 o = { ax * (1.f/16.f), ay * (1.f/16.f), az * (1.f/16.f), aw * (1.f/16.f) };
  *(float4*)(ws + W16_OFF + ((size_t)(b * 256 + cell)) * D_ + q * 4) = o;
}

// ---------------- pool_rest: w8 AND w4 in one launch (both from w16) ----------------
__global__ __launch_bounds__(256) void pool_rest_kernel(float* __restrict__ ws) {
  int gid = blockIdx.x * 256 + threadIdx.x;
  if (gid < 196608) {
    int q = gid % 96;
    int c8 = (gid / 96) & 63;
    int b = gid / (96 * 64);
    int p = c8 >> 3, r = c8 & 7;
    const float4* w16b = (const float4*)(ws + W16_OFF + (size_t)b * 256 * D_);
    float ax = 0.f, ay = 0.f, az = 0.f, aw = 0.f;
    #pragma unroll
    for (int a = 0; a < 2; ++a)
      #pragma unroll
      for (int c = 0; c < 2; ++c) {
        int cell = (p * 2 + a) * 16 + (r * 2 + c);
        float4 v = w16b[(size_t)cell * 96 + q];
        ax += v.x; ay += v.y; az += v.z; aw += v.w;
      }
    float4 o = { ax * 0.25f, ay * 0.25f, az * 0.25f, aw * 0.25f };
    *(float4*)(ws + W8_OFF + ((size_t)(b * 64 + c8)) * D_ + q * 4) = o;
  } else {
    int idx = gid - 196608;            // 0..49151
    int q = idx % 96;
    int c4 = (idx / 96) & 15;
    int b = idx / (96 * 16);
    int p = c4 >> 2, r = c4 & 3;
    const float4* w16b = (const float4*)(ws + W16_OFF + (size_t)b * 256 * D_);
    float ax = 0.f, ay = 0.f, az = 0.f, aw = 0.f;   // w4 accum
    #pragma unroll
    for (int a = 0; a < 2; ++a)
      #pragma unroll
      for (int c = 0; c < 2; ++c) {
        int p8 = p * 2 + a, r8 = r * 2 + c;
        float bx = 0.f, by = 0.f, bz = 0.f, bw = 0.f; // w8 accum (fresh, like pool8)
        #pragma unroll
        for (int a2 = 0; a2 < 2; ++a2)
          #pragma unroll
          for (int c2 = 0; c2 < 2; ++c2) {
            int cell = (p8 * 2 + a2) * 16 + (r8 * 2 + c2);
            float4 v = w16b[(size_t)cell * 96 + q];
            bx += v.x; by += v.y; bz += v.z; bw += v.w;
          }
        bx *= 0.25f; by *= 0.25f; bz *= 0.25f; bw *= 0.25f;
        ax += bx; ay += by; az += bz; aw += bw;
      }
    float4 o = { ax * 0.25f, ay * 0.25f, az * 0.25f, aw * 0.25f };
    *(float4*)(ws + W4_OFF + ((size_t)(b * 16 + c4)) * D_ + q * 4) = o;
  }
}

// ---------------- k-means++ v1 (R6-proven, 24.4us) + x10 rep PROBE ----------------
// Body identical to R6. rep loop is idempotent (same seeds -> same indices ->
// same outputs each rep); barriers fence cross-rep hazards.
__global__ __launch_bounds__(512) void kmeans_kernel(const float* __restrict__ ws,
                                                     float* __restrict__ out) {
  int blk = blockIdx.x;
  int si = blk / 32;
  int b  = blk % 32;
  int n  = (si == 0) ? 16 : (si == 1) ? 64 : 256;

  const float* pooled;
  if (si == 0)      pooled = ws + W4_OFF  + (size_t)b * 16  * D_;
  else if (si == 1) pooled = ws + W8_OFF  + (size_t)b * 64  * D_;
  else              pooled = ws + W16_OFF + (size_t)b * 256 * D_;
  float* ob = out + ((size_t)b * 12 + si * 4) * D_;

  __shared__ __align__(16) float4 csh4[96];   // one center row
  __shared__ float minsq[256];
  __shared__ uint32_t skey[3][2];
  __shared__ int sidx;
  __shared__ float ssum;
  __shared__ float wred[4];
  __shared__ float wmaxv[4];
  __shared__ int   wmaxi[4];

  int tid  = threadIdx.x;
  int row  = tid >> 1;        // 0..255
  int part = tid & 1;         // half-row owner
  int lane = tid & 63;
  int wv   = tid >> 6;

  #pragma unroll 1
  for (int rep = 0; rep < KM_REPS; ++rep) {

  if (tid == 0) {
    uint32_t f0, f1, bk0, bk1;
    tf2x32(0u, 42u, 0u, (uint32_t)si, f0, f1);
    tf2x32(f0, f1, 0u, (uint32_t)b, bk0, bk1);
    uint32_t k00, k01, k10, k11;
    tf2x32(bk0, bk1, 0u, 0u, k00, k01);     // k0 = split(bkey)[0]
    tf2x32(bk0, bk1, 0u, 1u, k10, k11);     // k1 = split(bkey)[1]
    uint32_t q0, q1, l0, l1;
    tf2x32(k00, k01, 0u, 1u, q0, q1);
    tf2x32(q0, q1, 0u, 0u, l0, l1);
    sidx = (int)((l0 ^ l1) & (uint32_t)(n - 1));
    for (int t = 0; t < 3; ++t) {           // step keys = split(k1, 3)
      uint32_t a, bb;
      tf2x32(k10, k11, 0u, (uint32_t)t, a, bb);
      skey[t][0] = a; skey[t][1] = bb;
    }
  }
  if (tid < 256) minsq[tid] = 0.f;

  // load this thread's half-row into registers (loop-invariant -> hoistable)
  float4 xr[48];
  if (row < n) {
    const float4* rp = (const float4*)(pooled + (size_t)row * D_ + part * 192);
    #pragma unroll
    for (int k = 0; k < 48; ++k) xr[k] = rp[k];
  }
  __syncthreads();   // sidx + minsq ready

  // c0: owners write their registers to LDS + output slot 0
  if (row == sidx) {
    float4* cb = csh4 + part * 48;
    float4* op = (float4*)(ob + part * 192);
    #pragma unroll
    for (int k = 0; k < 48; ++k) { cb[k] = xr[k]; op[k] = xr[k]; }
  }
  __syncthreads();

  // min_sq = ||x - c0||^2
  if (row < n) {
    float acc = 0.f;
    #pragma unroll
    for (int k = 0; k < 48; ++k) {
      float4 c4 = csh4[part * 48 + k];
      float dx = xr[k].x - c4.x, dy = xr[k].y - c4.y;
      float dz = xr[k].z - c4.z, dw = xr[k].w - c4.w;
      acc += dx * dx; acc += dy * dy; acc += dz * dz; acc += dw * dw;
    }
    acc += __shfl_xor(acc, 1);              // combine the 2 half-rows
    if (part == 0) minsq[row] = acc;
  }
  __syncthreads();

  const float TINY = __uint_as_float(0x00800000u);  // f32 tiny

  for (int t = 0; t < 3; ++t) {
    // --- parallel sum(min_sq) over 256 slots (zeros pad) ---
    if (tid < 256) {
      float v = minsq[tid];
      #pragma unroll
      for (int m = 1; m < 64; m <<= 1) v += __shfl_xor(v, m);
      if (lane == 0) wred[wv] = v;
    }
    __syncthreads();
    if (tid == 0) ssum = ((wred[0] + wred[1]) + (wred[2] + wred[3])) + 1e-8f;
    __syncthreads();

    // --- z_i = gumbel_i + log(prob_i + 1e-12); argmax (first occurrence) ---
    if (tid < 256) {
      float z = -1e30f;
      if (tid < n) {
        float prob  = minsq[tid] / ssum;
        float logit = logf(prob + 1e-12f);
        uint32_t y0, y1;
        tf2x32(skey[t][0], skey[t][1], 0u, (uint32_t)tid, y0, y1);
        uint32_t bits = y0 ^ y1;
        float f = __uint_as_float((bits >> 9) | 0x3F800000u) - 1.0f;
        float u = (f > 0.f) ? f : TINY;
        z = -logf(-logf(u)) + logit;
      }
      float bv = z; int bi = tid;
      #pragma unroll
      for (int m = 1; m < 64; m <<= 1) {
        float ov = __shfl_xor(bv, m);
        int   oi = __shfl_xor(bi, m);
        if (ov > bv || (ov == bv && oi < bi)) { bv = ov; bi = oi; }
      }
      if (lane == 0) { wmaxv[wv] = bv; wmaxi[wv] = bi; }
    }
    __syncthreads();
    if (tid == 0) {
      float cv = wmaxv[0]; int ci = wmaxi[0];
      for (int w2 = 1; w2 < 4; ++w2)
        if (wmaxv[w2] > cv || (wmaxv[w2] == cv && wmaxi[w2] < ci)) { cv = wmaxv[w2]; ci = wmaxi[w2]; }
      sidx = ci;
    }
    __syncthreads();

    // --- new center from owners' registers -> LDS + out ---
    if (row == sidx) {
      float4* cb = csh4 + part * 48;
      float4* op = (float4*)(ob + (size_t)(t + 1) * D_ + part * 192);
      #pragma unroll
      for (int k = 0; k < 48; ++k) { cb[k] = xr[k]; op[k] = xr[k]; }
    }
    __syncthreads();

    // --- min_sq = min(min_sq, ||x - c||^2) ---
    if (row < n) {
      float acc = 0.f;
      #pragma unroll
      for (int k = 0; k < 48; ++k) {
        float4 c4 = csh4[part * 48 + k];
        float dx = xr[k].x - c4.x, dy = xr[k].y - c4.y;
        float dz = xr[k].z - c4.z, dw = xr[k].w - c4.w;
        acc += dx * dx; acc += dy * dy; acc += dz * dz; acc += dw * dw;
      }
      acc += __shfl_xor(acc, 1);
      if (part == 0) minsq[row] = fminf(minsq[row], acc);
    }
    __syncthreads();
  }

  }  // rep
}

extern "C" void kernel_launch(void* const* d_in, const int* in_sizes, int n_in,
                              void* d_out, int out_size, void* d_ws, size_t ws_size,
                              hipStream_t stream) {
  const float* feats = (const float*)d_in[0];
  float* out = (float*)d_out;
  float* ws  = (float*)d_ws;   // uses 16,515,072 bytes

  pool16_kernel<<<2048, dim3(96, 4, 1), 0, stream>>>(feats, ws);
  pool_rest_kernel<<<960, 256, 0, stream>>>(ws);
  kmeans_kernel<<<96, 512, 0, stream>>>(ws, out);
}

// Round 12
// 63.520 us; speedup vs baseline: 4.2404x; 4.2404x over previous
//
#include <hip/hip_runtime.h>
#include <stdint.h>

#define D_ 384
#define NPTS 4096
// ws layout (floats): w4 [32*16*384] @0, w8 [32*64*384] @196608, w16 [32*256*384] @983040
#define W4_OFF 0
#define W8_OFF 196608
#define W16_OFF 983040

// ---------------- Threefry-2x32 (JAX-exact, 20 rounds) ----------------
__device__ __forceinline__ void tf_round(uint32_t& x0, uint32_t& x1, int r) {
  x0 += x1;
  x1 = (x1 << r) | (x1 >> (32 - r));
  x1 ^= x0;
}

__device__ void tf2x32(uint32_t k0, uint32_t k1, uint32_t x0, uint32_t x1,
                       uint32_t& y0, uint32_t& y1) {
  uint32_t ks2 = k0 ^ k1 ^ 0x1BD11BDAu;
  x0 += k0; x1 += k1;
  tf_round(x0, x1, 13); tf_round(x0, x1, 15); tf_round(x0, x1, 26); tf_round(x0, x1, 6);
  x0 += k1; x1 += ks2 + 1u;
  tf_round(x0, x1, 17); tf_round(x0, x1, 29); tf_round(x0, x1, 16); tf_round(x0, x1, 24);
  x0 += ks2; x1 += k0 + 2u;
  tf_round(x0, x1, 13); tf_round(x0, x1, 15); tf_round(x0, x1, 26); tf_round(x0, x1, 6);
  x0 += k0; x1 += k1 + 3u;
  tf_round(x0, x1, 17); tf_round(x0, x1, 29); tf_round(x0, x1, 16); tf_round(x0, x1, 24);
  x0 += k1; x1 += ks2 + 4u;
  tf_round(x0, x1, 13); tf_round(x0, x1, 15); tf_round(x0, x1, 26); tf_round(x0, x1, 6);
  x0 += ks2; x1 += k0 + 5u;
  y0 = x0; y1 = x1;
}

// ---------------- pool16: MEASURED ~31 us, HBM floor. Done. ----------------
__global__ __launch_bounds__(384) void pool16_kernel(const float* __restrict__ feats,
                                                     float* __restrict__ ws) {
  int blk = blockIdx.x;
  int b = blk >> 6;
  int cell = ((blk & 63) << 2) + threadIdx.y;
  int q = threadIdx.x;                 // 0..95
  int ch = cell >> 4, cw = cell & 15;
  const float* fb = feats + (size_t)b * NPTS * D_;
  float ax = 0.f, ay = 0.f, az = 0.f, aw = 0.f;
  #pragma unroll
  for (int dh = 0; dh < 4; ++dh) {
    int h = ch * 4 + dh;
    #pragma unroll
    for (int dw = 0; dw < 4; ++dw) {
      int w = cw * 4 + dw;
      float4 v = *(const float4*)(fb + ((size_t)(h * 64 + w)) * D_ + q * 4);
      ax += v.x; ay += v.y; az += v.z; aw += v.w;
    }
  }
  float4 o = { ax * (1.f/16.f), ay * (1.f/16.f), az * (1.f/16.f), aw * (1.f/16.f) };
  *(float4*)(ws + W16_OFF + ((size_t)(b * 256 + cell)) * D_ + q * 4) = o;
}

// ---------------- pool_rest: w8 AND w4 in one launch (both from w16) ----------------
__global__ __launch_bounds__(256) void pool_rest_kernel(float* __restrict__ ws) {
  int gid = blockIdx.x * 256 + threadIdx.x;
  if (gid < 196608) {
    int q = gid % 96;
    int c8 = (gid / 96) & 63;
    int b = gid / (96 * 64);
    int p = c8 >> 3, r = c8 & 7;
    const float4* w16b = (const float4*)(ws + W16_OFF + (size_t)b * 256 * D_);
    float ax = 0.f, ay = 0.f, az = 0.f, aw = 0.f;
    #pragma unroll
    for (int a = 0; a < 2; ++a)
      #pragma unroll
      for (int c = 0; c < 2; ++c) {
        int cell = (p * 2 + a) * 16 + (r * 2 + c);
        float4 v = w16b[(size_t)cell * 96 + q];
        ax += v.x; ay += v.y; az += v.z; aw += v.w;
      }
    float4 o = { ax * 0.25f, ay * 0.25f, az * 0.25f, aw * 0.25f };
    *(float4*)(ws + W8_OFF + ((size_t)(b * 64 + c8)) * D_ + q * 4) = o;
  } else {
    int idx = gid - 196608;            // 0..49151
    int q = idx % 96;
    int c4 = (idx / 96) & 15;
    int b = idx / (96 * 16);
    int p = c4 >> 2, r = c4 & 3;
    const float4* w16b = (const float4*)(ws + W16_OFF + (size_t)b * 256 * D_);
    float ax = 0.f, ay = 0.f, az = 0.f, aw = 0.f;   // w4 accum
    #pragma unroll
    for (int a = 0; a < 2; ++a)
      #pragma unroll
      for (int c = 0; c < 2; ++c) {
        int p8 = p * 2 + a, r8 = r * 2 + c;
        float bx = 0.f, by = 0.f, bz = 0.f, bw = 0.f; // w8 accum (fresh, like pool8)
        #pragma unroll
        for (int a2 = 0; a2 < 2; ++a2)
          #pragma unroll
          for (int c2 = 0; c2 < 2; ++c2) {
            int cell = (p8 * 2 + a2) * 16 + (r8 * 2 + c2);
            float4 v = w16b[(size_t)cell * 96 + q];
            bx += v.x; by += v.y; bz += v.z; bw += v.w;
          }
        bx *= 0.25f; by *= 0.25f; bz *= 0.25f; bw *= 0.25f;
        ax += bx; ay += by; az += bz; aw += bw;
      }
    float4 o = { ax * 0.25f, ay * 0.25f, az * 0.25f, aw * 0.25f };
    *(float4*)(ws + W4_OFF + ((size_t)(b * 16 + c4)) * D_ + q * 4) = o;
  }
}

// ---------------- k-means++ v5: 10 barriers (was 21), no ssum phase ----------------
// R11 counters: latency/barrier-bound (VALUBusy 5%, VGPR 120 — compiler reloads
// rows from L2 per pass; that's fine). Cuts: (1) z = g + __logf(minsq) — ssum
// cancels under argmax (eps-term only matters for m<1e-5 rows which can't win);
// (2) all-thread redundant argmax combine (no tid0 phase); (3) skip last
// distance pass; (4) csh4 padded part*49 (2 b128 addrs no longer same-bank).
__global__ __launch_bounds__(512) void kmeans_kernel(const float* __restrict__ ws,
                                                     float* __restrict__ out) {
  int blk = blockIdx.x;
  int si = blk >> 5;
  int b  = blk & 31;
  int n  = (si == 0) ? 16 : (si == 1) ? 64 : 256;

  const float* pooled;
  if (si == 0)      pooled = ws + W4_OFF  + (size_t)b * 16  * D_;
  else if (si == 1) pooled = ws + W8_OFF  + (size_t)b * 64  * D_;
  else              pooled = ws + W16_OFF + (size_t)b * 256 * D_;
  float* ob = out + ((size_t)b * 12 + si * 4) * D_;

  __shared__ __align__(16) float4 csh4[98];   // padded: part*49+k
  __shared__ float minsq[256];
  __shared__ uint32_t skey[3][2];
  __shared__ int sidx0;
  __shared__ float wmaxv[4];
  __shared__ int   wmaxi[4];

  int tid  = threadIdx.x;
  int row  = tid >> 1;        // 0..255
  int part = tid & 1;         // half-row owner
  int lane = tid & 63;
  int wv   = tid >> 6;

  // ---- load half-row (compiler may rematerialize; that's fine per R11) ----
  float4 xr[48];
  if (row < n) {
    const float4* rp = (const float4*)(pooled + (size_t)row * D_ + part * 192);
    #pragma unroll
    for (int k = 0; k < 48; ++k) xr[k] = rp[k];
  }
  if (tid < 256) minsq[tid] = 0.f;

  // ---- seeding: wave 0, branch-free lane-parallel threefry (R9-proven) ----
  if (tid < 64) {
    uint32_t f0, f1, bk0, bk1, r0, r1, s0, s1, e0, e1;
    tf2x32(0u, 42u, 0u, (uint32_t)si, f0, f1);
    tf2x32(f0, f1, 0u, (uint32_t)b, bk0, bk1);
    uint32_t cC = (tid < 3) ? 1u : 0u;
    tf2x32(bk0, bk1, 0u, cC, r0, r1);                 // lanes 0-2: k1; lane 3: k0
    uint32_t cD = (tid < 3) ? (uint32_t)tid : 1u;
    tf2x32(r0, r1, 0u, cD, s0, s1);                   // lanes 0-2: skey[t]; lane 3: q
    tf2x32(s0, s1, 0u, 0u, e0, e1);                   // lane 3: l
    if (tid < 3) { skey[tid][0] = s0; skey[tid][1] = s1; }
    else if (tid == 3) sidx0 = (int)((e0 ^ e1) & (uint32_t)(n - 1));
  }
  __syncthreads();                                     // B1: sidx0/skey/minsq-pad

  // ---- c0 broadcast ----
  int s = sidx0;
  if (row == s) {
    float4* cb = csh4 + part * 49;
    float4* op = (float4*)(ob + part * 192);
    #pragma unroll
    for (int k = 0; k < 48; ++k) { cb[k] = xr[k]; op[k] = xr[k]; }
  }
  __syncthreads();                                     // B2: csh4 ready

  // ---- min_sq = ||x - c0||^2 ----
  if (row < n) {
    float acc = 0.f;
    #pragma unroll
    for (int k = 0; k < 48; ++k) {
      float4 c4 = csh4[part * 49 + k];
      float dx = xr[k].x - c4.x, dy = xr[k].y - c4.y;
      float dz = xr[k].z - c4.z, dw = xr[k].w - c4.w;
      acc += dx * dx; acc += dy * dy; acc += dz * dz; acc += dw * dw;
    }
    acc += __shfl_xor(acc, 1);
    if (part == 0) minsq[row] = acc;
  }
  __syncthreads();                                     // B3: minsq ready

  const float TINY = __uint_as_float(0x00800000u);  // f32 tiny

  #pragma unroll 1
  for (int t = 0; t < 3; ++t) {
    // --- z = gumbel + log(minsq); per-wave argmax (no sum/div phase) ---
    if (tid < 256) {
      float z = -1e30f;
      if (tid < n) {
        float m = minsq[tid];
        uint32_t y0, y1;
        tf2x32(skey[t][0], skey[t][1], 0u, (uint32_t)tid, y0, y1);
        uint32_t bits = y0 ^ y1;
        float f = __uint_as_float((bits >> 9) | 0x3F800000u) - 1.0f;
        float u = (f > 0.f) ? f : TINY;
        z = -__logf(-__logf(u)) + __logf(m);   // m==0 -> -inf, never wins
      }
      float bv = z; int bi = tid;
      #pragma unroll
      for (int m2 = 1; m2 < 64; m2 <<= 1) {
        float ov = __shfl_xor(bv, m2);
        int   oi = __shfl_xor(bi, m2);
        if (ov > bv || (ov == bv && oi < bi)) { bv = ov; bi = oi; }
      }
      if (lane == 0) { wmaxv[wv] = bv; wmaxi[wv] = bi; }
    }
    __syncthreads();                                   // B4: wmax ready

    // --- all threads combine redundantly (broadcast reads, no extra barrier) ---
    float cv = wmaxv[0]; int ci = wmaxi[0];
    #pragma unroll
    for (int w2 = 1; w2 < 4; ++w2)
      if (wmaxv[w2] > cv || (wmaxv[w2] == cv && wmaxi[w2] < ci)) { cv = wmaxv[w2]; ci = wmaxi[w2]; }
    s = ci;

    // --- owners write out (+ csh4 only if another distance pass follows) ---
    if (row == s) {
      float4* op = (float4*)(ob + (size_t)(t + 1) * D_ + part * 192);
      float4* cb = csh4 + part * 49;
      #pragma unroll
      for (int k = 0; k < 48; ++k) { op[k] = xr[k]; if (t < 2) cb[k] = xr[k]; }
    }
    if (t < 2) {
      __syncthreads();                                 // B5: csh4 ready
      if (row < n) {
        float acc = 0.f;
        #pragma unroll
        for (int k = 0; k < 48; ++k) {
          float4 c4 = csh4[part * 49 + k];
          float dx = xr[k].x - c4.x, dy = xr[k].y - c4.y;
          float dz = xr[k].z - c4.z, dw = xr[k].w - c4.w;
          acc += dx * dx; acc += dy * dy; acc += dz * dz; acc += dw * dw;
        }
        acc += __shfl_xor(acc, 1);
        if (part == 0) minsq[row] = fminf(minsq[row], acc);
      }
      __syncthreads();                                 // B6: minsq ready
    }
  }
}

extern "C" void kernel_launch(void* const* d_in, const int* in_sizes, int n_in,
                              void* d_out, int out_size, void* d_ws, size_t ws_size,
                              hipStream_t stream) {
  const float* feats = (const float*)d_in[0];
  float* out = (float*)d_out;
  float* ws  = (float*)d_ws;   // uses 16,515,072 bytes

  pool16_kernel<<<2048, dim3(96, 4, 1), 0, stream>>>(feats, ws);
  pool_rest_kernel<<<960, 256, 0, stream>>>(ws);
  kmeans_kernel<<<96, 512, 0, stream>>>(ws, out);
}